// Round 12
// baseline (397.471 us; speedup 1.0000x reference)
//
#include <hip/hip_runtime.h>
#include <hip/hip_bf16.h>
#include <cstdint>
#include <cstddef>

#define NN 50000
#define RR 4
#define EE 400000
#define TE (RR*EE)
#define HR 25000         // hist bins per range (2 ranges * 25000 = 50000); 50KB LDS
#define RN (RR*NN)       // 200000
#define NSEG (NN*RR)     // 200000 (d-major, r-minor segments)
#define SCB2 782         // ceil(NSEG/256)
#define NBK 512          // dst buckets for the partition
#define BKSZ 98          // nodes per bucket (512*98 >= 50000)
#define CHA 4000         // edges per phase-A block (100 chunks/relation)
#define MAXSPAN 4608     // LDS image capacity (avg span ~3136)

using frag_ab = __attribute__((ext_vector_type(8))) short;   // 8 bf16 (4 VGPRs)
using frag_cd = __attribute__((ext_vector_type(4))) float;   // 4 fp32

static __device__ __forceinline__ unsigned short f2bf(float f) {
    union { float f; unsigned u; } v; v.f = f;
    unsigned r = (v.u + 0x7FFF + ((v.u >> 16) & 1)) >> 16;   // RNE
    return (unsigned short)r;
}
static __device__ __forceinline__ unsigned pack2(float lo, float hi) {
    return (unsigned)f2bf(lo) | ((unsigned)f2bf(hi) << 16);
}
static __device__ __forceinline__ float blo(unsigned u) { return __uint_as_float(u << 16); }
static __device__ __forceinline__ float bhi(unsigned u) { return __uint_as_float(u & 0xFFFF0000u); }

// ---------------- k_pre: degree histograms + x/basis converts (one launch) ----
// blocks [0,64): hist; [64,1627): x->bf16; [1627,1707): Bt. (R9-validated)
__global__ __launch_bounds__(1024) void k_pre(const int* __restrict__ src,
                                              const int* __restrict__ dst,
                                              int* __restrict__ cnt_srcQ,
                                              int* __restrict__ cnt_dstQ,
                                              const float4* __restrict__ x4,
                                              uint2* __restrict__ o,
                                              const float* __restrict__ B0,
                                              const float* __restrict__ B1,
                                              const float* __restrict__ B2,
                                              unsigned short* __restrict__ Bt0,
                                              unsigned short* __restrict__ Bt1,
                                              unsigned short* __restrict__ Bt2) {
    __shared__ unsigned bins[HR / 2];   // 12500 uints = 50 KB
    int bid = blockIdx.x;
    if (bid < 64) {
        int combo = bid >> 3;           // 0..7 : (r, side)
        int range = (bid >> 2) & 1;     // 0..1
        int qc    = bid & 3;            // 0..3
        int r = combo >> 1;
        int side = combo & 1;
        const int* arr = (side == 0 ? src : dst) + (size_t)r * EE + (size_t)qc * (EE / 4);
        int lo = range * HR;
        for (int i = threadIdx.x; i < HR / 2; i += 1024) bins[i] = 0;
        __syncthreads();
        const int4* a4 = (const int4*)arr;
        for (int i = threadIdx.x; i < EE / 16; i += 1024) {
            int4 v = a4[i];
            int t;
            t = v.x - lo; if ((unsigned)t < (unsigned)HR) atomicAdd(&bins[t >> 1], 1u << ((t & 1) * 16));
            t = v.y - lo; if ((unsigned)t < (unsigned)HR) atomicAdd(&bins[t >> 1], 1u << ((t & 1) * 16));
            t = v.z - lo; if ((unsigned)t < (unsigned)HR) atomicAdd(&bins[t >> 1], 1u << ((t & 1) * 16));
            t = v.w - lo; if ((unsigned)t < (unsigned)HR) atomicAdd(&bins[t >> 1], 1u << ((t & 1) * 16));
        }
        __syncthreads();
        int* outp = (side == 0 ? cnt_srcQ : cnt_dstQ) + (size_t)qc * RN + (size_t)r * NN + lo;
        for (int i = threadIdx.x; i < HR / 2; i += 1024) {
            unsigned b = bins[i];
            outp[2 * i]     = (int)(b & 0xFFFFu);
            outp[2 * i + 1] = (int)(b >> 16);
        }
    } else if (bid < 1627) {
        int i = (bid - 64) * 1024 + threadIdx.x;
        if (i < NN * 32) {
            float4 v = x4[i];
            o[i] = make_uint2(pack2(v.x, v.y), pack2(v.z, v.w));
        }
    } else {
        int t = (bid - 1627) * 1024 + threadIdx.x;   // [0, 81920)
        if (t < 32768) {
            int k = t & 255, n = t >> 8;
            Bt0[t] = f2bf(B0[k * 128 + n]);
        } else if (t < 65536) {
            int i = t - 32768;
            int k = i & 255, n = i >> 8;
            Bt1[i] = f2bf(B1[k * 128 + n]);
        } else {
            int i = t - 65536;
            int k = i & 255, n = i >> 8;
            Bt2[i] = f2bf(B2[k * 64 + n]);
        }
    }
}

// ---------------- k_norms_partial: norms + cntd2 + per-block partial sums ----
// (R9-validated) d-major (f = d*4+r) so partial sums line up with the scan.
__global__ __launch_bounds__(256) void k_norms_partial(const int* __restrict__ cnt_srcQ,
                                                       const int* __restrict__ cnt_dstQ,
                                                       float* __restrict__ nsrc,
                                                       float* __restrict__ ndst,
                                                       int* __restrict__ cntd2,
                                                       int* __restrict__ part) {
    __shared__ int s[256];
    int t = threadIdx.x;
    int f = blockIdx.x * 256 + t;
    int v = 0;
    if (f < NSEG) {
        int d = f >> 2, r = f & 3;
        int i = r * NN + d;
        int ss = cnt_srcQ[i] + cnt_srcQ[RN + i] + cnt_srcQ[2 * RN + i] + cnt_srcQ[3 * RN + i];
        int ds = cnt_dstQ[i] + cnt_dstQ[RN + i] + cnt_dstQ[2 * RN + i] + cnt_dstQ[3 * RN + i];
        nsrc[i] = 1.0f / sqrtf(fmaxf((float)ss, 1.0f));
        ndst[i] = 1.0f / sqrtf(fmaxf((float)ds, 1.0f));
        cntd2[f] = ds;
        v = ds;
    }
    s[t] = v;
    __syncthreads();
    for (int off = 128; off > 0; off >>= 1) {
        if (t < off) s[t] += s[t + off];
        __syncthreads();
    }
    if (t == 0) part[blockIdx.x] = s[0];
}

// ---------------- k_emit2: block-prefix + scan + rp2 + gcur (R9-validated) ----
__global__ __launch_bounds__(256) void k_emit2(const int* __restrict__ cntd2,
                                               const int* __restrict__ part,
                                               int* __restrict__ rp2,
                                               int* __restrict__ gcur) {
    __shared__ int red[256];
    __shared__ int s[256];
    int t = threadIdx.x;
    int bid = blockIdx.x;
    // exclusive block prefix
    int acc = 0;
    for (int j = t; j < bid; j += 256) acc += part[j];
    red[t] = acc;
    __syncthreads();
    for (int off = 128; off > 0; off >>= 1) {
        if (t < off) red[t] += red[t + off];
        __syncthreads();
    }
    int offs0 = red[0];
    __syncthreads();
    // in-block inclusive scan
    int f = bid * 256 + t;
    int v = (f < NSEG) ? cntd2[f] : 0;
    s[t] = v;
    __syncthreads();
    for (int off = 1; off < 256; off <<= 1) {
        int u = (t >= off) ? s[t - off] : 0;
        __syncthreads();
        s[t] += u;
        __syncthreads();
    }
    if (f < NSEG) {
        int rv = offs0 + s[t] - v;
        rp2[f] = rv;
        if (f % (BKSZ * 4) == 0) gcur[f / (BKSZ * 4)] = rv;
    }
    if (f == NSEG - 1) {
        rp2[NSEG] = TE;
        gcur[NBK - 1] = TE;   // 511*392 = 200312 > NSEG -> clamps to TE
    }
}

// ---------------- two-phase edge partition (validated) ----------
__global__ __launch_bounds__(256) void k_fillA(const int* __restrict__ src,
                                               const int* __restrict__ dst,
                                               int* __restrict__ gcur,
                                               unsigned* __restrict__ stage) {
    __shared__ int cnt[NBK];
    __shared__ int rcur[NBK];
    int r = blockIdx.y;
    int base_e = blockIdx.x * CHA;
    int t = threadIdx.x;
    for (int i = t; i < NBK; i += 256) cnt[i] = 0;
    __syncthreads();
    const int* dr = dst + (size_t)r * EE;
    const int* sr = src + (size_t)r * EE;
    for (int i = base_e + t; i < base_e + CHA; i += 256) {
        int d = dr[i];
        atomicAdd(&cnt[d / BKSZ], 1);
    }
    __syncthreads();
    for (int i = t; i < NBK; i += 256) rcur[i] = atomicAdd(&gcur[i], cnt[i]);
    __syncthreads();
    for (int i = base_e + t; i < base_e + CHA; i += 256) {
        int d = dr[i];
        int s = sr[i];
        int b = d / BKSZ;
        int dl = d - b * BKSZ;
        int pos = atomicAdd(&rcur[b], 1);
        stage[pos] = (unsigned)s | ((unsigned)r << 16) | ((unsigned)dl << 18);
    }
}

__global__ __launch_bounds__(256) void k_fillB(const unsigned* __restrict__ stage,
                                               const int* __restrict__ rp2,
                                               const float* __restrict__ nsrc,
                                               const float* __restrict__ ndst,
                                               uint2* __restrict__ ed) {
    __shared__ unsigned imgU[MAXSPAN];   // src | r<<16
    __shared__ float imgW[MAXSPAN];      // ns*nd
    __shared__ int lcur[BKSZ * 4];
    __shared__ float ndL[BKSZ * 4];
    int b = blockIdx.x;
    int t = threadIdx.x;
    int node0 = b * BKSZ;
    if (node0 >= NN) return;
    int nodes = min(BKSZ, NN - node0);
    int nseg_local = nodes * 4;
    int segbase = node0 * 4;
    for (int i = t; i < nseg_local; i += 256) {
        lcur[i] = rp2[segbase + i];
        ndL[i] = ndst[(i & 3) * NN + node0 + (i >> 2)];
    }
    __syncthreads();
    int S0 = rp2[segbase];
    int S1 = rp2[segbase + nseg_local];
    int span = S1 - S0;
    if (span <= MAXSPAN) {
        for (int i = S0 + t; i < S1; i += 256) {
            unsigned w = stage[i];
            int s = (int)(w & 0xFFFFu);
            int r = (int)((w >> 16) & 3u);
            int dl = (int)(w >> 18);
            int seg = dl * 4 + r;
            int pos = atomicAdd(&lcur[seg], 1);
            int idx = pos - S0;
            imgU[idx] = w & 0x3FFFFu;            // src | r<<16
            imgW[idx] = nsrc[r * NN + s] * ndL[seg];
        }
        __syncthreads();
        for (int i = t; i < span; i += 256)
            ed[S0 + i] = make_uint2(imgU[i], __float_as_uint(imgW[i]));
    } else {  // overflow fallback (statistically unreachable)
        for (int i = S0 + t; i < S1; i += 256) {
            unsigned w = stage[i];
            int s = (int)(w & 0xFFFFu);
            int r = (int)((w >> 16) & 3u);
            int dl = (int)(w >> 18);
            int seg = dl * 4 + r;
            int pos = atomicAdd(&lcur[seg], 1);
            ed[pos] = make_uint2(w & 0x3FFFFu,
                                 __float_as_uint(nsrc[r * NN + s] * ndL[seg]));
        }
    }
}

// ---------------- aggregation: R2-exact (measured best: 54.9us) -------------
__global__ __launch_bounds__(256) void k_agg(const uint4* __restrict__ hb4,
                                             const int* __restrict__ rp2,
                                             const uint2* __restrict__ ed,
                                             const float* __restrict__ coeff,
                                             uint2* __restrict__ Mb2) {
    int wave = (blockIdx.x * 256 + threadIdx.x) >> 6;
    int lane = threadIdx.x & 63;
    if (wave >= NN) return;
    int q = lane >> 4, hl = lane & 15;

    float c00 = coeff[0], c01 = coeff[1], c10 = coeff[2], c11 = coeff[3];
    float c20 = coeff[4], c21 = coeff[5], c30 = coeff[6], c31 = coeff[7];

    float a00 = 0.f, a01 = 0.f, a02 = 0.f, a03 = 0.f;
    float a04 = 0.f, a05 = 0.f, a06 = 0.f, a07 = 0.f;
    float a10 = 0.f, a11 = 0.f, a12 = 0.f, a13 = 0.f;
    float a14 = 0.f, a15 = 0.f, a16 = 0.f, a17 = 0.f;

    int e0 = rp2[wave * 4], e1 = rp2[wave * 4 + 4];

    int e = e0;
    uint2 wA = make_uint2(0u, 0u), wB = make_uint2(0u, 0u);
    if (e + 7 < e1) { wA = ed[e + q]; wB = ed[e + 4 + q]; }
    for (; e + 7 < e1; e += 8) {
        uint4 hA = hb4[(size_t)(wA.x & 0xFFFFu) * 16 + hl];
        uint4 hB = hb4[(size_t)(wB.x & 0xFFFFu) * 16 + hl];
        int eN = (e + 15 < e1) ? (e + 8) : e0;
        uint2 nA = ed[eN + q];
        uint2 nB = ed[eN + 4 + q];

        int rA = (int)(wA.x >> 16);
        int rB = (int)(wB.x >> 16);
        float wsA = __uint_as_float(wA.y);
        float wsB = __uint_as_float(wB.y);
        float wa0 = (rA == 0 ? c00 : rA == 1 ? c10 : rA == 2 ? c20 : c30) * wsA;
        float wa1 = (rA == 0 ? c01 : rA == 1 ? c11 : rA == 2 ? c21 : c31) * wsA;
        float wb0 = (rB == 0 ? c00 : rB == 1 ? c10 : rB == 2 ? c20 : c30) * wsB;
        float wb1 = (rB == 0 ? c01 : rB == 1 ? c11 : rB == 2 ? c21 : c31) * wsB;

        float h0 = blo(hA.x), h1 = bhi(hA.x), h2 = blo(hA.y), h3 = bhi(hA.y);
        float h4 = blo(hA.z), h5 = bhi(hA.z), h6 = blo(hA.w), h7 = bhi(hA.w);
        a00 += wa0 * h0; a01 += wa0 * h1; a02 += wa0 * h2; a03 += wa0 * h3;
        a04 += wa0 * h4; a05 += wa0 * h5; a06 += wa0 * h6; a07 += wa0 * h7;
        a10 += wa1 * h0; a11 += wa1 * h1; a12 += wa1 * h2; a13 += wa1 * h3;
        a14 += wa1 * h4; a15 += wa1 * h5; a16 += wa1 * h6; a17 += wa1 * h7;

        h0 = blo(hB.x); h1 = bhi(hB.x); h2 = blo(hB.y); h3 = bhi(hB.y);
        h4 = blo(hB.z); h5 = bhi(hB.z); h6 = blo(hB.w); h7 = bhi(hB.w);
        a00 += wb0 * h0; a01 += wb0 * h1; a02 += wb0 * h2; a03 += wb0 * h3;
        a04 += wb0 * h4; a05 += wb0 * h5; a06 += wb0 * h6; a07 += wb0 * h7;
        a10 += wb1 * h0; a11 += wb1 * h1; a12 += wb1 * h2; a13 += wb1 * h3;
        a14 += wb1 * h4; a15 += wb1 * h5; a16 += wb1 * h6; a17 += wb1 * h7;

        wA = nA; wB = nB;
    }
    for (; e < e1; e += 4) {
        int E = e + q;
        bool act = E < e1;
        uint2 weA = ed[act ? E : e0];
        uint4 hA = hb4[(size_t)(weA.x & 0xFFFFu) * 16 + hl];
        int rA = (int)(weA.x >> 16);
        float wsA = act ? __uint_as_float(weA.y) : 0.f;
        float wa0 = (rA == 0 ? c00 : rA == 1 ? c10 : rA == 2 ? c20 : c30) * wsA;
        float wa1 = (rA == 0 ? c01 : rA == 1 ? c11 : rA == 2 ? c21 : c31) * wsA;
        float h0 = blo(hA.x), h1 = bhi(hA.x), h2 = blo(hA.y), h3 = bhi(hA.y);
        float h4 = blo(hA.z), h5 = bhi(hA.z), h6 = blo(hA.w), h7 = bhi(hA.w);
        a00 += wa0 * h0; a01 += wa0 * h1; a02 += wa0 * h2; a03 += wa0 * h3;
        a04 += wa0 * h4; a05 += wa0 * h5; a06 += wa0 * h6; a07 += wa0 * h7;
        a10 += wa1 * h0; a11 += wa1 * h1; a12 += wa1 * h2; a13 += wa1 * h3;
        a14 += wa1 * h4; a15 += wa1 * h5; a16 += wa1 * h6; a17 += wa1 * h7;
    }

    // cross-quarter reduce (xor 16, then 32)
    a00 += __shfl_xor(a00, 16, 64); a00 += __shfl_xor(a00, 32, 64);
    a01 += __shfl_xor(a01, 16, 64); a01 += __shfl_xor(a01, 32, 64);
    a02 += __shfl_xor(a02, 16, 64); a02 += __shfl_xor(a02, 32, 64);
    a03 += __shfl_xor(a03, 16, 64); a03 += __shfl_xor(a03, 32, 64);
    a04 += __shfl_xor(a04, 16, 64); a04 += __shfl_xor(a04, 32, 64);
    a05 += __shfl_xor(a05, 16, 64); a05 += __shfl_xor(a05, 32, 64);
    a06 += __shfl_xor(a06, 16, 64); a06 += __shfl_xor(a06, 32, 64);
    a07 += __shfl_xor(a07, 16, 64); a07 += __shfl_xor(a07, 32, 64);
    a10 += __shfl_xor(a10, 16, 64); a10 += __shfl_xor(a10, 32, 64);
    a11 += __shfl_xor(a11, 16, 64); a11 += __shfl_xor(a11, 32, 64);
    a12 += __shfl_xor(a12, 16, 64); a12 += __shfl_xor(a12, 32, 64);
    a13 += __shfl_xor(a13, 16, 64); a13 += __shfl_xor(a13, 32, 64);
    a14 += __shfl_xor(a14, 16, 64); a14 += __shfl_xor(a14, 32, 64);
    a15 += __shfl_xor(a15, 16, 64); a15 += __shfl_xor(a15, 32, 64);
    a16 += __shfl_xor(a16, 16, 64); a16 += __shfl_xor(a16, 32, 64);
    a17 += __shfl_xor(a17, 16, 64); a17 += __shfl_xor(a17, 32, 64);

    // lane (q,hl): coeff c = q>>1, half h4 = q&1 -> channels hl*8 + h4*4 + 0..3
    int c = q >> 1, h4 = q & 1;
    float v0 = c ? (h4 ? a14 : a10) : (h4 ? a04 : a00);
    float v1 = c ? (h4 ? a15 : a11) : (h4 ? a05 : a01);
    float v2 = c ? (h4 ? a16 : a12) : (h4 ? a06 : a02);
    float v3 = c ? (h4 ? a17 : a13) : (h4 ? a07 : a03);
    uint2 st;
    st.x = pack2(v0, v1);
    st.y = pack2(v2, v3);
    Mb2[(size_t)wave * 64 + c * 32 + hl * 2 + h4] = st;
}

// ---------------- MFMA bf16 GEMM with LDS-staged A ----------------
// R10 diagnosis: direct A-fragment loads are 512B-strided per lane (16B used
// per 64B line, 4x over-fetch of 25.6MB Mb that misses per-XCD L2) -> k_gemm
// was ~25-28us, not ~10. Fix: block stages its 64x512B A-tile into LDS with
// fully-coalesced uint4 loads (each wave reads 1KB contiguous), XOR-swizzled
// (same validated involution as R7/R9 fused), then MFMA reads fragments from
// LDS. Last block: staged row clamped (stays inside d_ws), stores guarded.
template <int BN, bool BF16OUT>
__global__ __launch_bounds__(256) void k_gemm(const unsigned short* __restrict__ A,
                                              const unsigned short* __restrict__ Bt,
                                              void* __restrict__ Cout) {
    __shared__ char ldsA[64 * 512];   // 32 KB
    int tid = threadIdx.x;
    int row0 = blockIdx.x * 64;

    // stage: 8 iters x (8 rows x 512B); thread t -> row r8=t>>5, slot o16=t&31
    {
        int r8 = tid >> 5;
        int o16 = tid & 31;
#pragma unroll
        for (int it = 0; it < 8; it++) {
            int row = it * 8 + r8;                  // 0..63
            int grow = row0 + row;
            if (grow > NN - 1) grow = NN - 1;       // clamp: valid mem, garbage ok
            uint4 v = *(const uint4*)(A + (size_t)grow * 256 + o16 * 8);
            *(uint4*)(ldsA + row * 512 + ((o16 * 16) ^ ((row & 7) << 4))) = v;
        }
    }
    __syncthreads();

    int wave = tid >> 6, lane = tid & 63;
    int m = lane & 15, q = lane >> 4;
    const int NT = BN / 16;

    frag_cd acc[NT];
#pragma unroll
    for (int ct = 0; ct < NT; ct++) acc[ct] = (frag_cd){0.f, 0.f, 0.f, 0.f};

    int arow = wave * 16 + m;
#pragma unroll
    for (int kc = 0; kc < 8; kc++) {
        frag_ab a = *(const frag_ab*)(ldsA + arow * 512 +
                                      ((kc * 64 + q * 16) ^ ((arow & 7) << 4)));
#pragma unroll
        for (int ct = 0; ct < NT; ct++) {
            frag_ab b = *(const frag_ab*)(Bt + (size_t)(ct * 16 + m) * 256 + kc * 32 + q * 8);
            acc[ct] = __builtin_amdgcn_mfma_f32_16x16x32_bf16(a, b, acc[ct], 0, 0, 0);
        }
    }

#pragma unroll
    for (int ct = 0; ct < NT; ct++) {
#pragma unroll
        for (int i = 0; i < 4; i++) {
            int row = row0 + wave * 16 + q * 4 + i;
            if (row < NN) {
                int col = ct * 16 + m;
                float v = acc[ct][i];
                if (BF16OUT) {
                    v = fmaxf(v, 0.f);
                    ((unsigned short*)Cout)[(size_t)row * BN + col] = f2bf(v);
                } else {
                    ((float*)Cout)[(size_t)row * BN + col] = v;
                }
            }
        }
    }
}

// ---------------- host ----------------

extern "C" void kernel_launch(void* const* d_in, const int* in_sizes, int n_in,
                              void* d_out, int out_size, void* d_ws, size_t ws_size,
                              hipStream_t stream) {
    const float* x      = (const float*)d_in[0];
    const int*   src    = (const int*)d_in[1];
    const int*   dst    = (const int*)d_in[2];
    const float* basis0 = (const float*)d_in[3];
    const float* coeff0 = (const float*)d_in[4];
    const float* basis1 = (const float*)d_in[5];
    const float* coeff1 = (const float*)d_in[6];
    const float* basis2 = (const float*)d_in[7];
    const float* coeff2 = (const float*)d_in[8];
    float* out = (float*)d_out;

    char* p = (char*)d_ws;
    auto alloc = [&](size_t bytes) {
        char* r = p;
        p += (bytes + 255) & ~(size_t)255;
        return r;
    };
    int*   cnt_srcQ = (int*)alloc((size_t)4 * RN * 4);
    int*   cnt_dstQ = (int*)alloc((size_t)4 * RN * 4);
    float* nsrc     = (float*)alloc((size_t)RN * 4);
    float* ndst     = (float*)alloc((size_t)RN * 4);
    int*   cntd2    = (int*)alloc((size_t)NSEG * 4);
    int*   rp2      = (int*)alloc((size_t)(NSEG + 1) * 4);
    int*   part     = (int*)alloc((size_t)SCB2 * 4);
    int*   gcur     = (int*)alloc((size_t)NBK * 4);
    unsigned* stage = (unsigned*)alloc((size_t)TE * 4);
    uint2* ed       = (uint2*)alloc((size_t)TE * 8);
    unsigned* Mb    = (unsigned*)alloc((size_t)NN * 128 * 4);       // bf16 [N][256]
    unsigned* Hb    = (unsigned*)alloc((size_t)NN * 64 * 4);        // bf16 [N][128]
    unsigned* Xb    = (unsigned*)alloc((size_t)NN * 64 * 4);        // bf16 [N][128]
    unsigned short* Bt0 = (unsigned short*)alloc((size_t)128 * 256 * 2);
    unsigned short* Bt1 = (unsigned short*)alloc((size_t)128 * 256 * 2);
    unsigned short* Bt2 = (unsigned short*)alloc((size_t)64 * 256 * 2);

    // setup: 5 dispatches (R9-validated)
    k_pre<<<1707, 1024, 0, stream>>>(src, dst, cnt_srcQ, cnt_dstQ,
                                     (const float4*)x, (uint2*)Xb,
                                     basis0, basis1, basis2, Bt0, Bt1, Bt2);
    k_norms_partial<<<SCB2, 256, 0, stream>>>(cnt_srcQ, cnt_dstQ, nsrc, ndst, cntd2, part);
    k_emit2<<<SCB2, 256, 0, stream>>>(cntd2, part, rp2, gcur);
    k_fillA<<<dim3(EE / CHA, RR), 256, 0, stream>>>(src, dst, gcur, stage);
    k_fillB<<<NBK, 256, 0, stream>>>(stage, rp2, nsrc, ndst, ed);

    int aggBlocks = NN / 4;            // 12500
    int gemmBlocks = (NN + 63) / 64;   // 782

    // layer 0: Xb -> Mb -> Hb (relu, bf16)
    k_agg<<<aggBlocks, 256, 0, stream>>>((const uint4*)Xb, rp2, ed, coeff0, (uint2*)Mb);
    k_gemm<128, true><<<gemmBlocks, 256, 0, stream>>>((const unsigned short*)Mb, Bt0, Hb);
    // layer 1
    k_agg<<<aggBlocks, 256, 0, stream>>>((const uint4*)Hb, rp2, ed, coeff1, (uint2*)Mb);
    k_gemm<128, true><<<gemmBlocks, 256, 0, stream>>>((const unsigned short*)Mb, Bt1, Hb);
    // layer 2: final, fp32 out, no relu
    k_agg<<<aggBlocks, 256, 0, stream>>>((const uint4*)Hb, rp2, ed, coeff2, (uint2*)Mb);
    k_gemm<64, false><<<gemmBlocks, 256, 0, stream>>>((const unsigned short*)Mb, Bt2, out);
}

// Round 13
// 382.271 us; speedup vs baseline: 1.0398x; 1.0398x over previous
//
#include <hip/hip_runtime.h>
#include <hip/hip_bf16.h>
#include <cstdint>
#include <cstddef>

#define NN 50000
#define RR 4
#define EE 400000
#define TE (RR*EE)
#define HR 25000         // hist bins per range (2 ranges * 25000 = 50000); 50KB LDS
#define RN (RR*NN)       // 200000
#define NSEG (NN*RR)     // 200000 (d-major, r-minor segments)
#define SCB2 782         // ceil(NSEG/256)
#define NBK 512          // dst buckets for the partition
#define BKSZ 98          // nodes per bucket (512*98 >= 50000)
#define CHA 4000         // edges per phase-A block (100 chunks/relation)
#define MAXSPAN 4608     // LDS image capacity (avg span ~3136)

using frag_ab = __attribute__((ext_vector_type(8))) short;   // 8 bf16 (4 VGPRs)
using frag_cd = __attribute__((ext_vector_type(4))) float;   // 4 fp32

static __device__ __forceinline__ unsigned short f2bf(float f) {
    union { float f; unsigned u; } v; v.f = f;
    unsigned r = (v.u + 0x7FFF + ((v.u >> 16) & 1)) >> 16;   // RNE
    return (unsigned short)r;
}
static __device__ __forceinline__ unsigned pack2(float lo, float hi) {
    return (unsigned)f2bf(lo) | ((unsigned)f2bf(hi) << 16);
}
static __device__ __forceinline__ float blo(unsigned u) { return __uint_as_float(u << 16); }
static __device__ __forceinline__ float bhi(unsigned u) { return __uint_as_float(u & 0xFFFF0000u); }

// ---------------- k_pre: degree histograms + x/basis converts (one launch) ----
// blocks [0,64): hist; [64,1627): x->bf16; [1627,1707): Bt. (R9-validated)
__global__ __launch_bounds__(1024) void k_pre(const int* __restrict__ src,
                                              const int* __restrict__ dst,
                                              int* __restrict__ cnt_srcQ,
                                              int* __restrict__ cnt_dstQ,
                                              const float4* __restrict__ x4,
                                              uint2* __restrict__ o,
                                              const float* __restrict__ B0,
                                              const float* __restrict__ B1,
                                              const float* __restrict__ B2,
                                              unsigned short* __restrict__ Bt0,
                                              unsigned short* __restrict__ Bt1,
                                              unsigned short* __restrict__ Bt2) {
    __shared__ unsigned bins[HR / 2];   // 12500 uints = 50 KB
    int bid = blockIdx.x;
    if (bid < 64) {
        int combo = bid >> 3;           // 0..7 : (r, side)
        int range = (bid >> 2) & 1;     // 0..1
        int qc    = bid & 3;            // 0..3
        int r = combo >> 1;
        int side = combo & 1;
        const int* arr = (side == 0 ? src : dst) + (size_t)r * EE + (size_t)qc * (EE / 4);
        int lo = range * HR;
        for (int i = threadIdx.x; i < HR / 2; i += 1024) bins[i] = 0;
        __syncthreads();
        const int4* a4 = (const int4*)arr;
        for (int i = threadIdx.x; i < EE / 16; i += 1024) {
            int4 v = a4[i];
            int t;
            t = v.x - lo; if ((unsigned)t < (unsigned)HR) atomicAdd(&bins[t >> 1], 1u << ((t & 1) * 16));
            t = v.y - lo; if ((unsigned)t < (unsigned)HR) atomicAdd(&bins[t >> 1], 1u << ((t & 1) * 16));
            t = v.z - lo; if ((unsigned)t < (unsigned)HR) atomicAdd(&bins[t >> 1], 1u << ((t & 1) * 16));
            t = v.w - lo; if ((unsigned)t < (unsigned)HR) atomicAdd(&bins[t >> 1], 1u << ((t & 1) * 16));
        }
        __syncthreads();
        int* outp = (side == 0 ? cnt_srcQ : cnt_dstQ) + (size_t)qc * RN + (size_t)r * NN + lo;
        for (int i = threadIdx.x; i < HR / 2; i += 1024) {
            unsigned b = bins[i];
            outp[2 * i]     = (int)(b & 0xFFFFu);
            outp[2 * i + 1] = (int)(b >> 16);
        }
    } else if (bid < 1627) {
        int i = (bid - 64) * 1024 + threadIdx.x;
        if (i < NN * 32) {
            float4 v = x4[i];
            o[i] = make_uint2(pack2(v.x, v.y), pack2(v.z, v.w));
        }
    } else {
        int t = (bid - 1627) * 1024 + threadIdx.x;   // [0, 81920)
        if (t < 32768) {
            int k = t & 255, n = t >> 8;
            Bt0[t] = f2bf(B0[k * 128 + n]);
        } else if (t < 65536) {
            int i = t - 32768;
            int k = i & 255, n = i >> 8;
            Bt1[i] = f2bf(B1[k * 128 + n]);
        } else {
            int i = t - 65536;
            int k = i & 255, n = i >> 8;
            Bt2[i] = f2bf(B2[k * 64 + n]);
        }
    }
}

// ---------------- k_norms_partial: norms + cntd2 + per-block partial sums ----
__global__ __launch_bounds__(256) void k_norms_partial(const int* __restrict__ cnt_srcQ,
                                                       const int* __restrict__ cnt_dstQ,
                                                       float* __restrict__ nsrc,
                                                       float* __restrict__ ndst,
                                                       int* __restrict__ cntd2,
                                                       int* __restrict__ part) {
    __shared__ int s[256];
    int t = threadIdx.x;
    int f = blockIdx.x * 256 + t;
    int v = 0;
    if (f < NSEG) {
        int d = f >> 2, r = f & 3;
        int i = r * NN + d;
        int ss = cnt_srcQ[i] + cnt_srcQ[RN + i] + cnt_srcQ[2 * RN + i] + cnt_srcQ[3 * RN + i];
        int ds = cnt_dstQ[i] + cnt_dstQ[RN + i] + cnt_dstQ[2 * RN + i] + cnt_dstQ[3 * RN + i];
        nsrc[i] = 1.0f / sqrtf(fmaxf((float)ss, 1.0f));
        ndst[i] = 1.0f / sqrtf(fmaxf((float)ds, 1.0f));
        cntd2[f] = ds;
        v = ds;
    }
    s[t] = v;
    __syncthreads();
    for (int off = 128; off > 0; off >>= 1) {
        if (t < off) s[t] += s[t + off];
        __syncthreads();
    }
    if (t == 0) part[blockIdx.x] = s[0];
}

// ---------------- k_emit2: block-prefix + scan + rp2 + gcur (R9-validated) ----
__global__ __launch_bounds__(256) void k_emit2(const int* __restrict__ cntd2,
                                               const int* __restrict__ part,
                                               int* __restrict__ rp2,
                                               int* __restrict__ gcur) {
    __shared__ int red[256];
    __shared__ int s[256];
    int t = threadIdx.x;
    int bid = blockIdx.x;
    // exclusive block prefix
    int acc = 0;
    for (int j = t; j < bid; j += 256) acc += part[j];
    red[t] = acc;
    __syncthreads();
    for (int off = 128; off > 0; off >>= 1) {
        if (t < off) red[t] += red[t + off];
        __syncthreads();
    }
    int offs0 = red[0];
    __syncthreads();
    // in-block inclusive scan
    int f = bid * 256 + t;
    int v = (f < NSEG) ? cntd2[f] : 0;
    s[t] = v;
    __syncthreads();
    for (int off = 1; off < 256; off <<= 1) {
        int u = (t >= off) ? s[t - off] : 0;
        __syncthreads();
        s[t] += u;
        __syncthreads();
    }
    if (f < NSEG) {
        int rv = offs0 + s[t] - v;
        rp2[f] = rv;
        if (f % (BKSZ * 4) == 0) gcur[f / (BKSZ * 4)] = rv;
    }
    if (f == NSEG - 1) {
        rp2[NSEG] = TE;
        gcur[NBK - 1] = TE;   // 511*392 = 200312 > NSEG -> clamps to TE
    }
}

// ---------------- two-phase edge partition (validated) ----------
__global__ __launch_bounds__(256) void k_fillA(const int* __restrict__ src,
                                               const int* __restrict__ dst,
                                               int* __restrict__ gcur,
                                               unsigned* __restrict__ stage) {
    __shared__ int cnt[NBK];
    __shared__ int rcur[NBK];
    int r = blockIdx.y;
    int base_e = blockIdx.x * CHA;
    int t = threadIdx.x;
    for (int i = t; i < NBK; i += 256) cnt[i] = 0;
    __syncthreads();
    const int* dr = dst + (size_t)r * EE;
    const int* sr = src + (size_t)r * EE;
    for (int i = base_e + t; i < base_e + CHA; i += 256) {
        int d = dr[i];
        atomicAdd(&cnt[d / BKSZ], 1);
    }
    __syncthreads();
    for (int i = t; i < NBK; i += 256) rcur[i] = atomicAdd(&gcur[i], cnt[i]);
    __syncthreads();
    for (int i = base_e + t; i < base_e + CHA; i += 256) {
        int d = dr[i];
        int s = sr[i];
        int b = d / BKSZ;
        int dl = d - b * BKSZ;
        int pos = atomicAdd(&rcur[b], 1);
        stage[pos] = (unsigned)s | ((unsigned)r << 16) | ((unsigned)dl << 18);
    }
}

__global__ __launch_bounds__(256) void k_fillB(const unsigned* __restrict__ stage,
                                               const int* __restrict__ rp2,
                                               const float* __restrict__ nsrc,
                                               const float* __restrict__ ndst,
                                               uint2* __restrict__ ed) {
    __shared__ unsigned imgU[MAXSPAN];   // src | r<<16
    __shared__ float imgW[MAXSPAN];      // ns*nd
    __shared__ int lcur[BKSZ * 4];
    __shared__ float ndL[BKSZ * 4];
    int b = blockIdx.x;
    int t = threadIdx.x;
    int node0 = b * BKSZ;
    if (node0 >= NN) return;
    int nodes = min(BKSZ, NN - node0);
    int nseg_local = nodes * 4;
    int segbase = node0 * 4;
    for (int i = t; i < nseg_local; i += 256) {
        lcur[i] = rp2[segbase + i];
        ndL[i] = ndst[(i & 3) * NN + node0 + (i >> 2)];
    }
    __syncthreads();
    int S0 = rp2[segbase];
    int S1 = rp2[segbase + nseg_local];
    int span = S1 - S0;
    if (span <= MAXSPAN) {
        for (int i = S0 + t; i < S1; i += 256) {
            unsigned w = stage[i];
            int s = (int)(w & 0xFFFFu);
            int r = (int)((w >> 16) & 3u);
            int dl = (int)(w >> 18);
            int seg = dl * 4 + r;
            int pos = atomicAdd(&lcur[seg], 1);
            int idx = pos - S0;
            imgU[idx] = w & 0x3FFFFu;            // src | r<<16
            imgW[idx] = nsrc[r * NN + s] * ndL[seg];
        }
        __syncthreads();
        for (int i = t; i < span; i += 256)
            ed[S0 + i] = make_uint2(imgU[i], __float_as_uint(imgW[i]));
    } else {  // overflow fallback (statistically unreachable)
        for (int i = S0 + t; i < S1; i += 256) {
            unsigned w = stage[i];
            int s = (int)(w & 0xFFFFu);
            int r = (int)((w >> 16) & 3u);
            int dl = (int)(w >> 18);
            int seg = dl * 4 + r;
            int pos = atomicAdd(&lcur[seg], 1);
            ed[pos] = make_uint2(w & 0x3FFFFu,
                                 __float_as_uint(nsrc[r * NN + s] * ndL[seg]));
        }
    }
}

// ---------------- FUSED aggregation + GEMM, 256 threads, dynamic node queue --
// R9 champion (376.9us total, 87.7us/dispatch) + ONE change: waves claim nodes
// from an LDS atomic queue instead of static {w, w+4, w+8, w+12}. Block time
// was max over 4 waves of 4-node sums (~15-20% over mean); greedy claiming
// makes it ~(total+3*avg)/4. Cost: 16 LDS atomics + 1 extra barrier per block.
// Split-vs-fused economics (R12): per layer fused 87.8 < split 54.4+39.5.
template <int BN, bool BF16OUT>
__global__ __launch_bounds__(256) void k_agg_gemm(const uint4* __restrict__ hb4,
                                                  const int* __restrict__ rp2,
                                                  const uint2* __restrict__ ed,
                                                  const float* __restrict__ coeff,
                                                  const unsigned short* __restrict__ Bt,
                                                  void* __restrict__ Cout) {
    __shared__ uint4 ldsA4[16 * 32];   // 8 KB: 16 rows x 512B
    __shared__ int nextNode;
    char* ldsB = (char*)ldsA4;

    int w = threadIdx.x >> 6;          // wave 0..3
    int lane = threadIdx.x & 63;
    int q = lane >> 4, hl = lane & 15;
    int node0 = blockIdx.x * 16;

    if (threadIdx.x == 0) nextNode = 0;
    __syncthreads();

    float c00 = coeff[0], c01 = coeff[1], c10 = coeff[2], c11 = coeff[3];
    float c20 = coeff[4], c21 = coeff[5], c30 = coeff[6], c31 = coeff[7];

    for (;;) {
        int rowl = 0;
        if (lane == 0) rowl = atomicAdd(&nextNode, 1);
        rowl = __shfl(rowl, 0, 64);
        if (rowl >= 16) break;
        int node = node0 + rowl;        // always < NN (3125*16 == NN)
        {
            float a00 = 0.f, a01 = 0.f, a02 = 0.f, a03 = 0.f;
            float a04 = 0.f, a05 = 0.f, a06 = 0.f, a07 = 0.f;
            float a10 = 0.f, a11 = 0.f, a12 = 0.f, a13 = 0.f;
            float a14 = 0.f, a15 = 0.f, a16 = 0.f, a17 = 0.f;

            int e0 = rp2[node * 4], e1 = rp2[node * 4 + 4];
            int e = e0;
            uint2 wA = make_uint2(0u, 0u), wB = make_uint2(0u, 0u);
            if (e + 7 < e1) { wA = ed[e + q]; wB = ed[e + 4 + q]; }
            for (; e + 7 < e1; e += 8) {
                uint4 hA = hb4[(size_t)(wA.x & 0xFFFFu) * 16 + hl];
                uint4 hB = hb4[(size_t)(wB.x & 0xFFFFu) * 16 + hl];
                int eN = (e + 15 < e1) ? (e + 8) : e0;
                uint2 nA = ed[eN + q];
                uint2 nB = ed[eN + 4 + q];

                int rA = (int)(wA.x >> 16);
                int rB = (int)(wB.x >> 16);
                float wsA = __uint_as_float(wA.y);
                float wsB = __uint_as_float(wB.y);
                float wa0 = (rA == 0 ? c00 : rA == 1 ? c10 : rA == 2 ? c20 : c30) * wsA;
                float wa1 = (rA == 0 ? c01 : rA == 1 ? c11 : rA == 2 ? c21 : c31) * wsA;
                float wb0 = (rB == 0 ? c00 : rB == 1 ? c10 : rB == 2 ? c20 : c30) * wsB;
                float wb1 = (rB == 0 ? c01 : rB == 1 ? c11 : rB == 2 ? c21 : c31) * wsB;

                float h0 = blo(hA.x), h1 = bhi(hA.x), h2 = blo(hA.y), h3 = bhi(hA.y);
                float h4 = blo(hA.z), h5 = bhi(hA.z), h6 = blo(hA.w), h7 = bhi(hA.w);
                a00 += wa0 * h0; a01 += wa0 * h1; a02 += wa0 * h2; a03 += wa0 * h3;
                a04 += wa0 * h4; a05 += wa0 * h5; a06 += wa0 * h6; a07 += wa0 * h7;
                a10 += wa1 * h0; a11 += wa1 * h1; a12 += wa1 * h2; a13 += wa1 * h3;
                a14 += wa1 * h4; a15 += wa1 * h5; a16 += wa1 * h6; a17 += wa1 * h7;

                h0 = blo(hB.x); h1 = bhi(hB.x); h2 = blo(hB.y); h3 = bhi(hB.y);
                h4 = blo(hB.z); h5 = bhi(hB.z); h6 = blo(hB.w); h7 = bhi(hB.w);
                a00 += wb0 * h0; a01 += wb0 * h1; a02 += wb0 * h2; a03 += wb0 * h3;
                a04 += wb0 * h4; a05 += wb0 * h5; a06 += wb0 * h6; a07 += wb0 * h7;
                a10 += wb1 * h0; a11 += wb1 * h1; a12 += wb1 * h2; a13 += wb1 * h3;
                a14 += wb1 * h4; a15 += wb1 * h5; a16 += wb1 * h6; a17 += wb1 * h7;

                wA = nA; wB = nB;
            }
            for (; e < e1; e += 4) {    // masked tail: 1 edge/quarter
                int E = e + q;
                bool act = E < e1;
                uint2 weA = ed[act ? E : e0];
                uint4 hA = hb4[(size_t)(weA.x & 0xFFFFu) * 16 + hl];
                int rA = (int)(weA.x >> 16);
                float wsA = act ? __uint_as_float(weA.y) : 0.f;
                float wa0 = (rA == 0 ? c00 : rA == 1 ? c10 : rA == 2 ? c20 : c30) * wsA;
                float wa1 = (rA == 0 ? c01 : rA == 1 ? c11 : rA == 2 ? c21 : c31) * wsA;
                float h0 = blo(hA.x), h1 = bhi(hA.x), h2 = blo(hA.y), h3 = bhi(hA.y);
                float h4 = blo(hA.z), h5 = bhi(hA.z), h6 = blo(hA.w), h7 = bhi(hA.w);
                a00 += wa0 * h0; a01 += wa0 * h1; a02 += wa0 * h2; a03 += wa0 * h3;
                a04 += wa0 * h4; a05 += wa0 * h5; a06 += wa0 * h6; a07 += wa0 * h7;
                a10 += wa1 * h0; a11 += wa1 * h1; a12 += wa1 * h2; a13 += wa1 * h3;
                a14 += wa1 * h4; a15 += wa1 * h5; a16 += wa1 * h6; a17 += wa1 * h7;
            }

            // cross-quarter reduce (xor 16, then 32)
            a00 += __shfl_xor(a00, 16, 64); a00 += __shfl_xor(a00, 32, 64);
            a01 += __shfl_xor(a01, 16, 64); a01 += __shfl_xor(a01, 32, 64);
            a02 += __shfl_xor(a02, 16, 64); a02 += __shfl_xor(a02, 32, 64);
            a03 += __shfl_xor(a03, 16, 64); a03 += __shfl_xor(a03, 32, 64);
            a04 += __shfl_xor(a04, 16, 64); a04 += __shfl_xor(a04, 32, 64);
            a05 += __shfl_xor(a05, 16, 64); a05 += __shfl_xor(a05, 32, 64);
            a06 += __shfl_xor(a06, 16, 64); a06 += __shfl_xor(a06, 32, 64);
            a07 += __shfl_xor(a07, 16, 64); a07 += __shfl_xor(a07, 32, 64);
            a10 += __shfl_xor(a10, 16, 64); a10 += __shfl_xor(a10, 32, 64);
            a11 += __shfl_xor(a11, 16, 64); a11 += __shfl_xor(a11, 32, 64);
            a12 += __shfl_xor(a12, 16, 64); a12 += __shfl_xor(a12, 32, 64);
            a13 += __shfl_xor(a13, 16, 64); a13 += __shfl_xor(a13, 32, 64);
            a14 += __shfl_xor(a14, 16, 64); a14 += __shfl_xor(a14, 32, 64);
            a15 += __shfl_xor(a15, 16, 64); a15 += __shfl_xor(a15, 32, 64);
            a16 += __shfl_xor(a16, 16, 64); a16 += __shfl_xor(a16, 32, 64);
            a17 += __shfl_xor(a17, 16, 64); a17 += __shfl_xor(a17, 32, 64);

            // lane (q,hl): c = q>>1, h4 = q&1 -> channels hl*8 + h4*4 + 0..3
            int c = q >> 1, h4 = q & 1;
            float v0 = c ? (h4 ? a14 : a10) : (h4 ? a04 : a00);
            float v1 = c ? (h4 ? a15 : a11) : (h4 ? a05 : a01);
            float v2 = c ? (h4 ? a16 : a12) : (h4 ? a06 : a02);
            float v3 = c ? (h4 ? a17 : a13) : (h4 ? a07 : a03);
            uint2 st;
            st.x = pack2(v0, v1);
            st.y = pack2(v2, v3);
            int idx8 = c * 32 + hl * 2 + h4;                       // 8B unit index
            int boff = rowl * 512 + ((idx8 * 8) ^ ((rowl & 7) << 4));
            *(uint2*)(ldsB + boff) = st;
        }
    }
    __syncthreads();

    // ---- GEMM phase: C[16,BN] = ldsA[16,256] @ Bt^T; 4 waves split columns ----
    int m = lane & 15, qq = lane >> 4;
    constexpr int NTW = BN / 64;       // col tiles per wave (2 for 128, 1 for 64)

    frag_cd acc[NTW];
#pragma unroll
    for (int t = 0; t < NTW; t++) acc[t] = (frag_cd){0.f, 0.f, 0.f, 0.f};

    int arow = m;
#pragma unroll
    for (int kc = 0; kc < 8; kc++) {
        int aoff = arow * 512 + ((qq * 16 + kc * 64) ^ ((arow & 7) << 4));
        frag_ab a = *(const frag_ab*)(ldsB + aoff);
#pragma unroll
        for (int t = 0; t < NTW; t++) {
            int ct = w * NTW + t;
            frag_ab b = *(const frag_ab*)(Bt + (size_t)(ct * 16 + m) * 256 + kc * 32 + qq * 8);
            acc[t] = __builtin_amdgcn_mfma_f32_16x16x32_bf16(a, b, acc[t], 0, 0, 0);
        }
    }

#pragma unroll
    for (int t = 0; t < NTW; t++) {
#pragma unroll
        for (int i = 0; i < 4; i++) {
            int row = node0 + qq * 4 + i;
            int col = (w * NTW + t) * 16 + m;
            float v = acc[t][i];
            if (BF16OUT) {
                v = fmaxf(v, 0.f);
                ((unsigned short*)Cout)[(size_t)row * BN + col] = f2bf(v);
            } else {
                ((float*)Cout)[(size_t)row * BN + col] = v;
            }
        }
    }
}

// ---------------- host ----------------

extern "C" void kernel_launch(void* const* d_in, const int* in_sizes, int n_in,
                              void* d_out, int out_size, void* d_ws, size_t ws_size,
                              hipStream_t stream) {
    const float* x      = (const float*)d_in[0];
    const int*   src    = (const int*)d_in[1];
    const int*   dst    = (const int*)d_in[2];
    const float* basis0 = (const float*)d_in[3];
    const float* coeff0 = (const float*)d_in[4];
    const float* basis1 = (const float*)d_in[5];
    const float* coeff1 = (const float*)d_in[6];
    const float* basis2 = (const float*)d_in[7];
    const float* coeff2 = (const float*)d_in[8];
    float* out = (float*)d_out;

    char* p = (char*)d_ws;
    auto alloc = [&](size_t bytes) {
        char* r = p;
        p += (bytes + 255) & ~(size_t)255;
        return r;
    };
    int*   cnt_srcQ = (int*)alloc((size_t)4 * RN * 4);
    int*   cnt_dstQ = (int*)alloc((size_t)4 * RN * 4);
    float* nsrc     = (float*)alloc((size_t)RN * 4);
    float* ndst     = (float*)alloc((size_t)RN * 4);
    int*   cntd2    = (int*)alloc((size_t)NSEG * 4);
    int*   rp2      = (int*)alloc((size_t)(NSEG + 1) * 4);
    int*   part     = (int*)alloc((size_t)SCB2 * 4);
    int*   gcur     = (int*)alloc((size_t)NBK * 4);
    unsigned* stage = (unsigned*)alloc((size_t)TE * 4);
    uint2* ed       = (uint2*)alloc((size_t)TE * 8);
    unsigned* Hb    = (unsigned*)alloc((size_t)NN * 64 * 4);        // bf16 [N][128]
    unsigned* Hb2   = (unsigned*)alloc((size_t)NN * 64 * 4);        // bf16 [N][128]
    unsigned* Xb    = (unsigned*)alloc((size_t)NN * 64 * 4);        // bf16 [N][128]
    unsigned short* Bt0 = (unsigned short*)alloc((size_t)128 * 256 * 2);
    unsigned short* Bt1 = (unsigned short*)alloc((size_t)128 * 256 * 2);
    unsigned short* Bt2 = (unsigned short*)alloc((size_t)64 * 256 * 2);

    // setup: 5 dispatches (R9-validated)
    k_pre<<<1707, 1024, 0, stream>>>(src, dst, cnt_srcQ, cnt_dstQ,
                                     (const float4*)x, (uint2*)Xb,
                                     basis0, basis1, basis2, Bt0, Bt1, Bt2);
    k_norms_partial<<<SCB2, 256, 0, stream>>>(cnt_srcQ, cnt_dstQ, nsrc, ndst, cntd2, part);
    k_emit2<<<SCB2, 256, 0, stream>>>(cntd2, part, rp2, gcur);
    k_fillA<<<dim3(EE / CHA, RR), 256, 0, stream>>>(src, dst, gcur, stage);
    k_fillB<<<NBK, 256, 0, stream>>>(stage, rp2, nsrc, ndst, ed);

    int fusedBlocks = NN / 16;   // 3125, exact

    // layer 0: Xb -> Hb (relu, bf16)
    k_agg_gemm<128, true><<<fusedBlocks, 256, 0, stream>>>(
        (const uint4*)Xb, rp2, ed, coeff0, Bt0, Hb);
    // layer 1: Hb -> Hb2 (double-buffered: in-place would race)
    k_agg_gemm<128, true><<<fusedBlocks, 256, 0, stream>>>(
        (const uint4*)Hb, rp2, ed, coeff1, Bt1, Hb2);
    // layer 2: Hb2 -> out (fp32, no relu)
    k_agg_gemm<64, false><<<fusedBlocks, 256, 0, stream>>>(
        (const uint4*)Hb2, rp2, ed, coeff2, Bt2, out);
}